// Round 11
// baseline (233.794 us; speedup 1.0000x reference)
//
#include <hip/hip_runtime.h>

#define NPTS     16384
#define G        20
#define G2       400
#define ORIGIN   -5.0f
#define INV_CELL 2.0f
#define D2MAX    0.25f     // EPS^2 sentinel: contributes exactly 0 after sqrt

#define KNN_GRID  2048     // 8192 waves (= wave-slot capacity), stealing loop
#define KNN_BLOCK 256

// ---- ws layout (bytes) ----
#define OFF_COUNTS   0u        // u32[8192]
#define OFF_STARTS   32768u    // u32[8192]
#define OFF_CURSORS  65536u    // u32[8192] (scan seeds with starts; scatter bumps)
#define OFF_WLCNT    98304u    // u32
#define OFF_WCUR     98308u    // u32 work-steal cursor
#define OFF_WL       98432u    // int2[12288] (worst case 12192 entries)
#define OFF_EOFF     196736u   // u32[8192]
#define OFF_PTS      262144u   // float4[16384], cell-sorted
#define OFF_PART     589824u   // float[12288] per-entry partials
#define WS_REQUIRED  638976u

__device__ __forceinline__ int cell_of(float x, float y, float z) {
  int cx = (int)floorf((x - ORIGIN) * INV_CELL); cx = min(max(cx, 0), G - 1);
  int cy = (int)floorf((y - ORIGIN) * INV_CELL); cy = min(max(cy, 0), G - 1);
  int cz = (int)floorf((z - ORIGIN) * INV_CELL); cz = min(max(cz, 0), G - 1);
  return (cx * G + cy) * G + cz;
}

// K0: zero counts (32 KB) + {wlcnt, wcur, pad, pad}.
__global__ __launch_bounds__(256) void prep_zero_kernel(unsigned char* ws) {
  uint4* p = (uint4*)(ws + OFF_COUNTS);
  const int i = blockIdx.x * 256 + threadIdx.x;   // 2048 threads x 16 B
  p[i] = make_uint4(0u, 0u, 0u, 0u);
  if (i == 0) *(uint4*)(ws + OFF_WLCNT) = make_uint4(0u, 0u, 0u, 0u);
}

// K1: histogram (16384 threads, global atomics).
__global__ __launch_bounds__(256) void prep_hist_kernel(const float* __restrict__ q,
                                                        unsigned char* ws) {
  unsigned* counts = (unsigned*)(ws + OFF_COUNTS);
  const int i = blockIdx.x * 256 + threadIdx.x;
  atomicAdd(counts + cell_of(q[3 * i], q[3 * i + 1], q[3 * i + 2]), 1u);
}

// K2: scan — 1024 threads, shfl-based hierarchical scan (2 barriers).
__global__ __launch_bounds__(1024) void prep_scan_kernel(unsigned char* ws) {
  unsigned* counts  = (unsigned*)(ws + OFF_COUNTS);
  unsigned* starts  = (unsigned*)(ws + OFF_STARTS);
  unsigned* cursors = (unsigned*)(ws + OFF_CURSORS);
  unsigned* eoff    = (unsigned*)(ws + OFF_EOFF);
  unsigned* wlcnt   = (unsigned*)(ws + OFF_WLCNT);

  const int t = threadIdx.x, lane = t & 63, wid = t >> 6;
  unsigned c8[8];
  unsigned mycnt = 0, myent = 0;
#pragma unroll
  for (int i = 0; i < 8; ++i) {
    c8[i] = counts[t * 8 + i];
    mycnt += c8[i];
    myent += (c8[i] + 1u) >> 1;
  }
  // wave-inclusive scan of per-thread sums
  unsigned vs = mycnt, ve = myent;
#pragma unroll
  for (int d = 1; d < 64; d <<= 1) {
    const unsigned t1 = __shfl_up(vs, d);
    const unsigned t2 = __shfl_up(ve, d);
    if (lane >= d) { vs += t1; ve += t2; }
  }
  __shared__ unsigned wt[16], we[16];
  if (lane == 63) { wt[wid] = vs; we[wid] = ve; }
  __syncthreads();
  if (t < 16) {   // wave 0 lanes 0..15: exclusive scan of the 16 wave totals
    const unsigned oa = wt[t], ob = we[t];
    unsigned a = oa, b = ob;
#pragma unroll
    for (int d = 1; d < 16; d <<= 1) {
      const unsigned t1 = __shfl_up(a, d);
      const unsigned t2 = __shfl_up(b, d);
      if (t >= d) { a += t1; b += t2; }
    }
    wt[t] = a - oa;   // exclusive wave prefix
    we[t] = b - ob;
  }
  __syncthreads();
  unsigned run  = wt[wid] + (vs - mycnt);   // exclusive prefix (cells)
  unsigned erun = we[wid] + (ve - myent);   // exclusive prefix (entries)
#pragma unroll
  for (int i = 0; i < 8; ++i) {
    const int c = t * 8 + i;
    starts[c]  = run;
    cursors[c] = run;                // scatter cursor seeded at cell start
    eoff[c]    = erun;
    run  += c8[i];
    erun += (c8[i] + 1u) >> 1;
  }
  if (t == 1023) *wlcnt = erun;      // grand total entries
}

// K3: scatter (cid recomputed) + emit pair-entries (threads < 8192).
__global__ __launch_bounds__(256) void prep_scatter_emit_kernel(
    const float* __restrict__ q, unsigned char* ws) {
  const unsigned* counts  = (const unsigned*)(ws + OFF_COUNTS);
  const unsigned* starts  = (const unsigned*)(ws + OFF_STARTS);
  unsigned*       cursors = (unsigned*)(ws + OFF_CURSORS);
  const unsigned* eoff    = (const unsigned*)(ws + OFF_EOFF);
  int2*           wl      = (int2*)(ws + OFF_WL);
  float4*         pts     = (float4*)(ws + OFF_PTS);

  const int i = blockIdx.x * 256 + threadIdx.x;   // 16384 threads
  const float x = q[3 * i], y = q[3 * i + 1], z = q[3 * i + 2];
  const int cid = cell_of(x, y, z);
  const unsigned pos = atomicAdd(cursors + cid, 1u);
  pts[pos] = make_float4(x, y, z, 0.0f);

  if (i < 8192) {
    const unsigned n = counts[i];
    if (n) {
      const unsigned base = eoff[i];
      const int st = (int)starts[i];
      const unsigned ne = (n + 1u) >> 1;
      for (unsigned g2 = 0; g2 < ne; ++g2) {
        const unsigned rem = n - 2u * g2;
        const int c2 = rem < 2u ? (int)rem : 2;
        wl[base + g2] = make_int2(st + 2 * (int)g2, (i << 4) | c2);
      }
    }
  }
}

// K4: wave-per-pair-entry with WORK STEALING (one pop per entry; part[e]
// depends only on e -> deterministic) and a 2-WIDE inner loop (two
// independent L2 loads in flight per iteration halves exposed latency).
// No fences, no LDS, no cross-wave merge. Reduce is a separate kernel.
__global__ __launch_bounds__(KNN_BLOCK) void knn_cells_kernel(unsigned char* ws) {
  const unsigned* starts = (const unsigned*)(ws + OFF_STARTS);
  const int2*     wl     = (const int2*)(ws + OFF_WL);
  const float4*   pts    = (const float4*)(ws + OFF_PTS);
  float*          part   = (float*)(ws + OFF_PART);
  unsigned*       wcur   = (unsigned*)(ws + OFF_WCUR);
  const int wlc = (int)*(const unsigned*)(ws + OFF_WLCNT);

  const int lane = threadIdx.x & 63;
  const unsigned DXC = 10569u;  // {0,1,-1,0,0,1,1,-1,-1}  2-bit (d+1) codes
  const unsigned DYC = 34965u;  // {0,0,0,1,-1,1,-1,1,-1}

  for (;;) {
    int e = 0;
    if (lane == 0) e = (int)atomicAdd(wcur, 1u);
    e = __shfl(e, 0);
    if (e >= wlc) break;

    const int2 ent   = wl[e];
    const int qstart = ent.x;
    const int cell   = ent.y >> 4;
    const int cnt    = ent.y & 15;   // 1 or 2

    float qx[2], qy[2], qz[2];
#pragma unroll
    for (int k = 0; k < 2; ++k) {
      if (k < cnt) {
        const float4 Q = pts[qstart + k];
        qx[k] = Q.x; qy[k] = Q.y; qz[k] = Q.z;
      } else {  // dummy query far away: never passes threshold
        qx[k] = 1.0e4f; qy[k] = 1.0e4f; qz[k] = 1.0e4f;
      }
    }

    float P[2][5];
#pragma unroll
    for (int k = 0; k < 2; ++k)
#pragma unroll
      for (int s = 0; s < 5; ++s) P[k][s] = D2MAX;

    const int cx  = cell / G2;
    const int rem = cell - cx * G2;
    const int cy  = rem / G;
    const int cz  = rem - cy * G;
    const int zlo = cz > 0 ? cz - 1 : 0;
    const int zhi = cz < G - 1 ? cz + 1 : G - 1;

    // Prefetch all 9 column range bounds (independent loads)
    int rs[9], re[9];
#pragma unroll
    for (int r = 0; r < 9; ++r) {
      const int dx = (int)((DXC >> (2 * r)) & 3u) - 1;
      const int dy = (int)((DYC >> (2 * r)) & 3u) - 1;
      const int nx = cx + dx, ny = cy + dy;
      if ((unsigned)nx < (unsigned)G && (unsigned)ny < (unsigned)G) {
        const int colbase = (nx * G + ny) * G;
        rs[r] = (int)starts[colbase + zlo];
        re[r] = (int)starts[colbase + zhi + 1];
      } else {
        rs[r] = 0; re[r] = 0;
      }
    }

#pragma unroll
    for (int r = 0; r < 9; ++r) {
      const int s0 = rs[r], e0 = re[r];
      for (int j = s0; j < e0; j += 128) {
        const int ia = j + lane;
        const int ib = ia + 64;
        const bool va = ia < e0;
        const bool vb = ib < e0;
        const float4 A = pts[va ? ia : e0 - 1];   // both loads issue together
        const float4 B = pts[vb ? ib : e0 - 1];
#pragma unroll
        for (int k = 0; k < 2; ++k) {
          const float dax = qx[k] - A.x, day = qy[k] - A.y, daz = qz[k] - A.z;
          float v = fmaf(daz, daz, fmaf(day, day, dax * dax));
          if (!va) v = 1.0e9f;
          if (v < P[k][4] && v != 0.0f) {   // self -> exactly 0, excluded
            P[k][4] = fmaxf(P[k][3], fminf(v, P[k][4]));
            P[k][3] = fmaxf(P[k][2], fminf(v, P[k][3]));
            P[k][2] = fmaxf(P[k][1], fminf(v, P[k][2]));
            P[k][1] = fmaxf(P[k][0], fminf(v, P[k][1]));
            P[k][0] = fminf(P[k][0], v);
          }
          const float dbx = qx[k] - B.x, dby = qy[k] - B.y, dbz = qz[k] - B.z;
          float w = fmaf(dbz, dbz, fmaf(dby, dby, dbx * dbx));
          if (!vb) w = 1.0e9f;
          if (w < P[k][4] && w != 0.0f) {
            P[k][4] = fmaxf(P[k][3], fminf(w, P[k][4]));
            P[k][3] = fmaxf(P[k][2], fminf(w, P[k][3]));
            P[k][2] = fmaxf(P[k][1], fminf(w, P[k][2]));
            P[k][1] = fmaxf(P[k][0], fminf(w, P[k][1]));
            P[k][0] = fminf(P[k][0], w);
          }
        }
      }
    }

    // Epilogue: exact top-8 per query from the 64x5 pool (ascending ->
    // deterministic; m <= 0.25 always; sentinel -> +0).
    float accE = 0.0f;
#pragma unroll
    for (int k = 0; k < 2; ++k) {
      if (k < cnt) {
        float a0 = P[k][0], a1 = P[k][1], a2 = P[k][2], a3 = P[k][3], a4 = P[k][4];
#pragma unroll
        for (int rr = 0; rr < 8; ++rr) {
          float m = a0;
          m = fminf(m, __shfl_xor(m, 1));
          m = fminf(m, __shfl_xor(m, 2));
          m = fminf(m, __shfl_xor(m, 4));
          m = fminf(m, __shfl_xor(m, 8));
          m = fminf(m, __shfl_xor(m, 16));
          m = fminf(m, __shfl_xor(m, 32));
          accE += 0.5f - sqrtf(m);
          const unsigned long long bal = __ballot(a0 == m);
          const int first = __ffsll(bal) - 1;
          const bool adv = (lane == first);
          a0 = adv ? a1 : a0;
          a1 = adv ? a2 : a1;
          a2 = adv ? a3 : a2;
          a3 = adv ? a4 : a3;
          a4 = adv ? D2MAX : a4;
        }
      }
    }

    if (lane == 0) part[e] = accE;
  }
}

// K5: final reduce, fixed order -> deterministic.
__global__ __launch_bounds__(256) void final_reduce2_kernel(const unsigned char* ws,
                                                            float* __restrict__ out) {
  const float* part = (const float*)(ws + OFF_PART);
  const int wlc = (int)*(const unsigned*)(ws + OFF_WLCNT);
  const int tid = threadIdx.x;
  float v = 0.0f;
  for (int i = tid; i < wlc; i += 256) v += part[i];
#pragma unroll
  for (int off = 1; off < 64; off <<= 1) v += __shfl_xor(v, off);
  __shared__ float r[4];
  if ((tid & 63) == 0) r[tid >> 6] = v;
  __syncthreads();
  if (tid == 0) out[0] = (r[0] + r[1] + r[2] + r[3]) * (1.0f / (float)NPTS);
}

// ---------------- v2 fallback (proven) if ws is too small ----------------
#define FB_TILE 2048
__global__ __launch_bounds__(512) void knn_loss_kernel(
    const float* __restrict__ q, float* __restrict__ block_sum) {
  __shared__ float4 tile[FB_TILE];
  __shared__ float  wsum[8];
  const int tid = threadIdx.x, lane = tid & 63, wave = tid >> 6;
  const int qbase = blockIdx.x * 32 + wave * 4;
  float qx[4], qy[4], qz[4], qq[4];
#pragma unroll
  for (int k = 0; k < 4; ++k) {
    const float x = q[3 * (qbase + k) + 0];
    const float y = q[3 * (qbase + k) + 1];
    const float z = q[3 * (qbase + k) + 2];
    qx[k] = x; qy[k] = y; qz[k] = z;
    qq[k] = fmaf(z, z, fmaf(y, y, x * x));
  }
  float L[4][8];
#pragma unroll
  for (int k = 0; k < 4; ++k)
#pragma unroll
    for (int s = 0; s < 8; ++s) L[k][s] = D2MAX;
  for (int t = 0; t < NPTS / FB_TILE; ++t) {
    const int tb = t * FB_TILE;
#pragma unroll
    for (int s2 = 0; s2 < FB_TILE / 512; ++s2) {
      const int p = s2 * 512 + tid, gp = tb + p;
      const float x = q[3 * gp], y = q[3 * gp + 1], z = q[3 * gp + 2];
      tile[p] = make_float4(x, y, z, fmaf(z, z, fmaf(y, y, x * x)));
    }
    __syncthreads();
#pragma unroll 2
    for (int s = 0; s < FB_TILE / 64; ++s) {
      const float4 p = tile[s * 64 + lane];
      float d2[4];
#pragma unroll
      for (int k = 0; k < 4; ++k) {
        const float dt = fmaf(qx[k], p.x, fmaf(qy[k], p.y, qz[k] * p.z));
        d2[k] = fmaf(-2.0f, dt, qq[k] + p.w);
      }
      unsigned long long m[4];
#pragma unroll
      for (int k = 0; k < 4; ++k) m[k] = __ballot(d2[k] < L[k][7]);
      if (m[0] | m[1] | m[2] | m[3]) {
        const int jb = tb + s * 64;
#pragma unroll
        for (int k = 0; k < 4; ++k) {
          unsigned long long mk = m[k];
          while (mk) {
            const int i = __ffsll(mk) - 1;
            mk &= mk - 1;
            const float v = __shfl(d2[k], i);
            if ((jb + i) != (qbase + k) && v < L[k][7]) {
              L[k][7] = fmaxf(L[k][6], fminf(v, L[k][7]));
              L[k][6] = fmaxf(L[k][5], fminf(v, L[k][6]));
              L[k][5] = fmaxf(L[k][4], fminf(v, L[k][5]));
              L[k][4] = fmaxf(L[k][3], fminf(v, L[k][4]));
              L[k][3] = fmaxf(L[k][2], fminf(v, L[k][3]));
              L[k][2] = fmaxf(L[k][1], fminf(v, L[k][2]));
              L[k][1] = fmaxf(L[k][0], fminf(v, L[k][1]));
              L[k][0] = fminf(L[k][0], v);
            }
          }
        }
      }
    }
    __syncthreads();
  }
  float acc = 0.0f;
#pragma unroll
  for (int k = 0; k < 4; ++k)
#pragma unroll
    for (int s = 0; s < 8; ++s) acc += 0.5f - sqrtf(fmaxf(L[k][s], 0.0f));
  if (lane == 0) wsum[wave] = acc;
  __syncthreads();
  if (tid == 0) {
    float s = 0.0f;
#pragma unroll
    for (int w = 0; w < 8; ++w) s += wsum[w];
    block_sum[blockIdx.x] = s;
  }
}

__global__ __launch_bounds__(256) void final_reduce_kernel(
    const float* __restrict__ bs, float* __restrict__ out) {
  const int tid = threadIdx.x;
  float v = bs[tid] + bs[tid + 256];
#pragma unroll
  for (int off = 1; off < 64; off <<= 1) v += __shfl_xor(v, off);
  __shared__ float r[4];
  if ((tid & 63) == 0) r[tid >> 6] = v;
  __syncthreads();
  if (tid == 0) out[0] = (r[0] + r[1] + r[2] + r[3]) * (1.0f / (float)NPTS);
}

extern "C" void kernel_launch(void* const* d_in, const int* in_sizes, int n_in,
                              void* d_out, int out_size, void* d_ws, size_t ws_size,
                              hipStream_t stream) {
  const float* q = (const float*)d_in[0];
  unsigned char* ws = (unsigned char*)d_ws;
  float* outp = (float*)d_out;
  if (ws_size >= WS_REQUIRED) {
    prep_zero_kernel<<<8, 256, 0, stream>>>(ws);
    prep_hist_kernel<<<64, 256, 0, stream>>>(q, ws);
    prep_scan_kernel<<<1, 1024, 0, stream>>>(ws);
    prep_scatter_emit_kernel<<<64, 256, 0, stream>>>(q, ws);
    knn_cells_kernel<<<KNN_GRID, KNN_BLOCK, 0, stream>>>(ws);
    final_reduce2_kernel<<<1, 256, 0, stream>>>(ws, outp);
  } else {
    float* block_sum = (float*)d_ws;
    knn_loss_kernel<<<512, 512, 0, stream>>>(q, block_sum);
    final_reduce_kernel<<<1, 256, 0, stream>>>(block_sum, outp);
  }
}

// Round 12
// 64.531 us; speedup vs baseline: 3.6230x; 3.6230x over previous
//
#include <hip/hip_runtime.h>

#define NPTS     16384
#define G        20
#define G2       400
#define ORIGIN   -5.0f
#define INV_CELL 2.0f
#define D2MAX    0.25f     // EPS^2 sentinel: contributes exactly 0 after sqrt
#define QPW      4         // queries per worklist entry

#define PREP_BLOCKS 8
#define KNN_GRID  3072     // 12288 wave slots >= worst-case 12096 entries
#define KNN_BLOCK 256

// ---- ws layout (bytes) ----
#define OFF_COUNTS   0u        // u32[8192]
#define OFF_STARTS   32768u    // u32[8192]
#define OFF_CURSORS  65536u    // u32[8192] (scan seeds with starts; scatter bumps)
#define OFF_WLCNT    98304u    // u32
#define OFF_BAR1     98308u    // u32 (prep barrier 1)
#define OFF_BAR2     98312u    // u32 (prep barrier 2)
#define OFF_WL       98432u    // int2[12288]
#define OFF_EOFF     196736u   // u32[8192]
#define OFF_PTS      262144u   // float4[16384], cell-sorted
#define OFF_PART     589824u   // float[12288] per-entry partials
#define WS_REQUIRED  638976u

__device__ __forceinline__ int cell_of(float x, float y, float z) {
  int cx = (int)floorf((x - ORIGIN) * INV_CELL); cx = min(max(cx, 0), G - 1);
  int cy = (int)floorf((y - ORIGIN) * INV_CELL); cy = min(max(cy, 0), G - 1);
  int cz = (int)floorf((z - ORIGIN) * INV_CELL); cz = min(max(cz, 0), G - 1);
  return (cx * G + cy) * G + cz;
}

// K0: zero counts (32 KB) + {wlcnt, bar1, bar2, pad}.
__global__ __launch_bounds__(256) void prep_zero_kernel(unsigned char* ws) {
  uint4* p = (uint4*)(ws + OFF_COUNTS);
  const int i = blockIdx.x * 256 + threadIdx.x;   // 2048 threads x 16 B
  p[i] = make_uint4(0u, 0u, 0u, 0u);
  if (i == 0) *(uint4*)(ws + OFF_WLCNT) = make_uint4(0u, 0u, 0u, 0u);
}

// 8-block spin barrier (release/acquire) — v10-proven pattern; 8 blocks of
// 1024 thr are trivially co-resident on 256 CUs.
__device__ __forceinline__ void gbar8(unsigned* bar) {
  __syncthreads();
  if (threadIdx.x == 0) {
    __threadfence();                    // release this block's writes
    atomicAdd(bar, 1u);
    while (atomicAdd(bar, 0u) < PREP_BLOCKS) __builtin_amdgcn_s_sleep(2);
    __threadfence();                    // acquire other blocks' writes
  }
  __syncthreads();
}

// K1: fused prep — hist -> bar -> scan(block 0) -> bar -> scatter+emit.
// 8 blocks x 1024 threads; each thread owns points gid and gid+8192 and cell gid.
__global__ __launch_bounds__(1024) void prep_fused_kernel(
    const float* __restrict__ q, unsigned char* ws) {
  unsigned* counts  = (unsigned*)(ws + OFF_COUNTS);
  unsigned* starts  = (unsigned*)(ws + OFF_STARTS);
  unsigned* cursors = (unsigned*)(ws + OFF_CURSORS);
  unsigned* eoff    = (unsigned*)(ws + OFF_EOFF);
  unsigned* wlcnt   = (unsigned*)(ws + OFF_WLCNT);
  unsigned* bar1    = (unsigned*)(ws + OFF_BAR1);
  unsigned* bar2    = (unsigned*)(ws + OFF_BAR2);
  int2*     wl      = (int2*)(ws + OFF_WL);
  float4*   pts     = (float4*)(ws + OFF_PTS);

  const int t   = threadIdx.x;
  const int gid = blockIdx.x * 1024 + t;          // 0..8191

  // ---- phase A: histogram (2 points/thread, coords stay in registers) ----
  const int i0 = gid, i1 = gid + 8192;
  const float x0 = q[3 * i0], y0 = q[3 * i0 + 1], z0 = q[3 * i0 + 2];
  const float x1 = q[3 * i1], y1 = q[3 * i1 + 1], z1 = q[3 * i1 + 2];
  const int c0 = cell_of(x0, y0, z0);
  const int c1 = cell_of(x1, y1, z1);
  atomicAdd(counts + c0, 1u);
  atomicAdd(counts + c1, 1u);

  gbar8(bar1);

  // ---- phase B: scan by block 0 (1024 thr x 8 cells, shfl hierarchical) ----
  if (blockIdx.x == 0) {
    const int lane = t & 63, wid = t >> 6;
    unsigned c8[8];
    unsigned mycnt = 0, myent = 0;
#pragma unroll
    for (int i = 0; i < 8; ++i) {
      c8[i] = counts[t * 8 + i];
      mycnt += c8[i];
      myent += (c8[i] + (QPW - 1u)) / QPW;
    }
    unsigned vs = mycnt, ve = myent;
#pragma unroll
    for (int d = 1; d < 64; d <<= 1) {
      const unsigned t1 = __shfl_up(vs, d);
      const unsigned t2 = __shfl_up(ve, d);
      if (lane >= d) { vs += t1; ve += t2; }
    }
    __shared__ unsigned wt[16], we[16];
    if (lane == 63) { wt[wid] = vs; we[wid] = ve; }
    __syncthreads();
    if (t < 16) {
      const unsigned oa = wt[t], ob = we[t];
      unsigned a = oa, b = ob;
#pragma unroll
      for (int d = 1; d < 16; d <<= 1) {
        const unsigned t1 = __shfl_up(a, d);
        const unsigned t2 = __shfl_up(b, d);
        if (t >= d) { a += t1; b += t2; }
      }
      wt[t] = a - oa;   // exclusive wave prefix
      we[t] = b - ob;
    }
    __syncthreads();
    unsigned run  = wt[wid] + (vs - mycnt);
    unsigned erun = we[wid] + (ve - myent);
#pragma unroll
    for (int i = 0; i < 8; ++i) {
      const int c = t * 8 + i;
      starts[c]  = run;
      cursors[c] = run;                // scatter cursor seeded at cell start
      eoff[c]    = erun;
      run  += c8[i];
      erun += (c8[i] + (QPW - 1u)) / QPW;
    }
    if (t == 1023) *wlcnt = erun;
  }

  gbar8(bar2);

  // ---- phase C: scatter (2 points/thread) + emit (cell gid) ----
  const unsigned p0 = atomicAdd(cursors + c0, 1u);
  pts[p0] = make_float4(x0, y0, z0, 0.0f);
  const unsigned p1 = atomicAdd(cursors + c1, 1u);
  pts[p1] = make_float4(x1, y1, z1, 0.0f);

  {
    const unsigned n = counts[gid];
    if (n) {
      const unsigned base = eoff[gid];
      const int st = (int)starts[gid];
      const unsigned ne = (n + (QPW - 1u)) / QPW;
      for (unsigned g2 = 0; g2 < ne; ++g2) {
        const unsigned rem = n - QPW * g2;
        const int c2 = rem < (unsigned)QPW ? (int)rem : QPW;
        wl[base + g2] = make_int2(st + QPW * (int)g2, (gid << 4) | c2);
      }
    }
  }
}

// K2: ONE WAVE per entry (<=4 queries of one cell), STATIC assignment,
// early exit — the proven v6 structure, QPW widened to 4 so each candidate
// load serves 4 queries. No LDS, no fences, no atomics.
__global__ __launch_bounds__(KNN_BLOCK) void knn_cells_kernel(unsigned char* ws) {
  const unsigned* starts = (const unsigned*)(ws + OFF_STARTS);
  const int2*     wl     = (const int2*)(ws + OFF_WL);
  const float4*   pts    = (const float4*)(ws + OFF_PTS);
  float*          part   = (float*)(ws + OFF_PART);
  const int wlc = (int)*(const unsigned*)(ws + OFF_WLCNT);

  const int lane = threadIdx.x & 63;
  const int e    = blockIdx.x * (KNN_BLOCK / 64) + (threadIdx.x >> 6);
  if (e >= wlc) return;

  // column visit order {dx,dy}: own column first, then faces, then corners
  const unsigned DXC = 10569u;  // {0,1,-1,0,0,1,1,-1,-1}  2-bit (d+1) codes
  const unsigned DYC = 34965u;  // {0,0,0,1,-1,1,-1,1,-1}

  const int2 ent   = wl[e];
  const int qstart = ent.x;
  const int cell   = ent.y >> 4;
  const int cnt    = ent.y & 15;   // 1..4

  float qx[QPW], qy[QPW], qz[QPW];
#pragma unroll
  for (int k = 0; k < QPW; ++k) {
    if (k < cnt) {
      const float4 Q = pts[qstart + k];
      qx[k] = Q.x; qy[k] = Q.y; qz[k] = Q.z;
    } else {  // dummy query far away: never passes threshold
      qx[k] = 1.0e4f; qy[k] = 1.0e4f; qz[k] = 1.0e4f;
    }
  }

  float P[QPW][5];
#pragma unroll
  for (int k = 0; k < QPW; ++k)
#pragma unroll
    for (int s = 0; s < 5; ++s) P[k][s] = D2MAX;

  const int cx  = cell / G2;
  const int rem = cell - cx * G2;
  const int cy  = rem / G;
  const int cz  = rem - cy * G;
  const int zlo = cz > 0 ? cz - 1 : 0;
  const int zhi = cz < G - 1 ? cz + 1 : G - 1;

  // Prefetch all 9 column range bounds (independent loads, one latency wall)
  int rs[9], re[9];
#pragma unroll
  for (int r = 0; r < 9; ++r) {
    const int dx = (int)((DXC >> (2 * r)) & 3u) - 1;
    const int dy = (int)((DYC >> (2 * r)) & 3u) - 1;
    const int nx = cx + dx, ny = cy + dy;
    if ((unsigned)nx < (unsigned)G && (unsigned)ny < (unsigned)G) {
      const int colbase = (nx * G + ny) * G;
      rs[r] = (int)starts[colbase + zlo];
      re[r] = (int)starts[colbase + zhi + 1];
    } else {
      rs[r] = 0; re[r] = 0;
    }
  }

#pragma unroll
  for (int r = 0; r < 9; ++r) {
    for (int j = rs[r]; j < re[r]; j += 64) {
      int idx = j + lane;
      const bool val = idx < re[r];
      if (!val) idx = re[r] - 1;
      const float4 Pt = pts[idx];
#pragma unroll
      for (int k = 0; k < QPW; ++k) {
        const float ddx = qx[k] - Pt.x;
        const float ddy = qy[k] - Pt.y;
        const float ddz = qz[k] - Pt.z;
        float v = fmaf(ddz, ddz, fmaf(ddy, ddy, ddx * ddx));
        if (!val) v = 1.0e9f;
        if (v < P[k][4] && v != 0.0f) {   // self -> exactly 0, excluded
          P[k][4] = fmaxf(P[k][3], fminf(v, P[k][4]));
          P[k][3] = fmaxf(P[k][2], fminf(v, P[k][3]));
          P[k][2] = fmaxf(P[k][1], fminf(v, P[k][2]));
          P[k][1] = fmaxf(P[k][0], fminf(v, P[k][1]));
          P[k][0] = fminf(P[k][0], v);
        }
      }
    }
  }

  // Epilogue: per query, sum relu-contributions of the 8 smallest of the
  // 64x5 pool. m <= 0.25 always; sentinel -> +0. Ascending -> deterministic.
  float accE = 0.0f;
#pragma unroll
  for (int k = 0; k < QPW; ++k) {
    if (k < cnt) {
      float a0 = P[k][0], a1 = P[k][1], a2 = P[k][2], a3 = P[k][3], a4 = P[k][4];
#pragma unroll
      for (int rr = 0; rr < 8; ++rr) {
        float m = a0;
        m = fminf(m, __shfl_xor(m, 1));
        m = fminf(m, __shfl_xor(m, 2));
        m = fminf(m, __shfl_xor(m, 4));
        m = fminf(m, __shfl_xor(m, 8));
        m = fminf(m, __shfl_xor(m, 16));
        m = fminf(m, __shfl_xor(m, 32));
        accE += 0.5f - sqrtf(m);
        const unsigned long long bal = __ballot(a0 == m);
        const int first = __ffsll(bal) - 1;
        const bool adv = (lane == first);
        a0 = adv ? a1 : a0;
        a1 = adv ? a2 : a1;
        a2 = adv ? a3 : a2;
        a3 = adv ? a4 : a3;
        a4 = adv ? D2MAX : a4;
      }
    }
  }

  if (lane == 0) part[e] = accE;
}

// K3: final reduce, fixed order -> deterministic.
__global__ __launch_bounds__(256) void final_reduce2_kernel(const unsigned char* ws,
                                                            float* __restrict__ out) {
  const float* part = (const float*)(ws + OFF_PART);
  const int wlc = (int)*(const unsigned*)(ws + OFF_WLCNT);
  const int tid = threadIdx.x;
  float v = 0.0f;
  for (int i = tid; i < wlc; i += 256) v += part[i];
#pragma unroll
  for (int off = 1; off < 64; off <<= 1) v += __shfl_xor(v, off);
  __shared__ float r[4];
  if ((tid & 63) == 0) r[tid >> 6] = v;
  __syncthreads();
  if (tid == 0) out[0] = (r[0] + r[1] + r[2] + r[3]) * (1.0f / (float)NPTS);
}

// ---------------- v2 fallback (proven) if ws is too small ----------------
#define FB_TILE 2048
__global__ __launch_bounds__(512) void knn_loss_kernel(
    const float* __restrict__ q, float* __restrict__ block_sum) {
  __shared__ float4 tile[FB_TILE];
  __shared__ float  wsum[8];
  const int tid = threadIdx.x, lane = tid & 63, wave = tid >> 6;
  const int qbase = blockIdx.x * 32 + wave * 4;
  float qx[4], qy[4], qz[4], qq[4];
#pragma unroll
  for (int k = 0; k < 4; ++k) {
    const float x = q[3 * (qbase + k) + 0];
    const float y = q[3 * (qbase + k) + 1];
    const float z = q[3 * (qbase + k) + 2];
    qx[k] = x; qy[k] = y; qz[k] = z;
    qq[k] = fmaf(z, z, fmaf(y, y, x * x));
  }
  float L[4][8];
#pragma unroll
  for (int k = 0; k < 4; ++k)
#pragma unroll
    for (int s = 0; s < 8; ++s) L[k][s] = D2MAX;
  for (int t = 0; t < NPTS / FB_TILE; ++t) {
    const int tb = t * FB_TILE;
#pragma unroll
    for (int s2 = 0; s2 < FB_TILE / 512; ++s2) {
      const int p = s2 * 512 + tid, gp = tb + p;
      const float x = q[3 * gp], y = q[3 * gp + 1], z = q[3 * gp + 2];
      tile[p] = make_float4(x, y, z, fmaf(z, z, fmaf(y, y, x * x)));
    }
    __syncthreads();
#pragma unroll 2
    for (int s = 0; s < FB_TILE / 64; ++s) {
      const float4 p = tile[s * 64 + lane];
      float d2[4];
#pragma unroll
      for (int k = 0; k < 4; ++k) {
        const float dt = fmaf(qx[k], p.x, fmaf(qy[k], p.y, qz[k] * p.z));
        d2[k] = fmaf(-2.0f, dt, qq[k] + p.w);
      }
      unsigned long long m[4];
#pragma unroll
      for (int k = 0; k < 4; ++k) m[k] = __ballot(d2[k] < L[k][7]);
      if (m[0] | m[1] | m[2] | m[3]) {
        const int jb = tb + s * 64;
#pragma unroll
        for (int k = 0; k < 4; ++k) {
          unsigned long long mk = m[k];
          while (mk) {
            const int i = __ffsll(mk) - 1;
            mk &= mk - 1;
            const float v = __shfl(d2[k], i);
            if ((jb + i) != (qbase + k) && v < L[k][7]) {
              L[k][7] = fmaxf(L[k][6], fminf(v, L[k][7]));
              L[k][6] = fmaxf(L[k][5], fminf(v, L[k][6]));
              L[k][5] = fmaxf(L[k][4], fminf(v, L[k][5]));
              L[k][4] = fmaxf(L[k][3], fminf(v, L[k][4]));
              L[k][3] = fmaxf(L[k][2], fminf(v, L[k][3]));
              L[k][2] = fmaxf(L[k][1], fminf(v, L[k][2]));
              L[k][1] = fmaxf(L[k][0], fminf(v, L[k][1]));
              L[k][0] = fminf(L[k][0], v);
            }
          }
        }
      }
    }
    __syncthreads();
  }
  float acc = 0.0f;
#pragma unroll
  for (int k = 0; k < 4; ++k)
#pragma unroll
    for (int s = 0; s < 8; ++s) acc += 0.5f - sqrtf(fmaxf(L[k][s], 0.0f));
  if (lane == 0) wsum[wave] = acc;
  __syncthreads();
  if (tid == 0) {
    float s = 0.0f;
#pragma unroll
    for (int w = 0; w < 8; ++w) s += wsum[w];
    block_sum[blockIdx.x] = s;
  }
}

__global__ __launch_bounds__(256) void final_reduce_kernel(
    const float* __restrict__ bs, float* __restrict__ out) {
  const int tid = threadIdx.x;
  float v = bs[tid] + bs[tid + 256];
#pragma unroll
  for (int off = 1; off < 64; off <<= 1) v += __shfl_xor(v, off);
  __shared__ float r[4];
  if ((tid & 63) == 0) r[tid >> 6] = v;
  __syncthreads();
  if (tid == 0) out[0] = (r[0] + r[1] + r[2] + r[3]) * (1.0f / (float)NPTS);
}

extern "C" void kernel_launch(void* const* d_in, const int* in_sizes, int n_in,
                              void* d_out, int out_size, void* d_ws, size_t ws_size,
                              hipStream_t stream) {
  const float* q = (const float*)d_in[0];
  unsigned char* ws = (unsigned char*)d_ws;
  float* outp = (float*)d_out;
  if (ws_size >= WS_REQUIRED) {
    prep_zero_kernel<<<8, 256, 0, stream>>>(ws);
    prep_fused_kernel<<<PREP_BLOCKS, 1024, 0, stream>>>(q, ws);
    knn_cells_kernel<<<KNN_GRID, KNN_BLOCK, 0, stream>>>(ws);
    final_reduce2_kernel<<<1, 256, 0, stream>>>(ws, outp);
  } else {
    float* block_sum = (float*)d_ws;
    knn_loss_kernel<<<512, 512, 0, stream>>>(q, block_sum);
    final_reduce_kernel<<<1, 256, 0, stream>>>(block_sum, outp);
  }
}